// Round 11
// baseline (19476.845 us; speedup 1.0000x reference)
//
#include <hip/hip_runtime.h>

// LSTM layer. Inputs f32, OUTPUT f32.
//
// R11: FUSED single persistent kernel. The separate x_gates GEMM (0.7ms) and
// its 1GB xg round-trip are deleted; the W_ih·x dot is computed per-step
// INSIDE the recurrence, placed BEFORE the h-poll so it executes in the
// shadow of the publish->LLC->poll round trip (R5-R10 established that RT,
// not weight delivery, is the floor: halving weight bytes in R10 moved step
// time only 2.08->1.98us).
//
// Structure (256 wgs = 1/CU, 1024 threads; wg=(batch b, quarter q); thread
// (rg,kc) owns 4 gate rows x 16 K): per step t:
//   a. x-dot(t+1): 4-row x 16K dot vs x(t+1) from LDS (partials in regs) +
//      issue global load of x(t+2)           <- fills the RT shadow
//   b. phase1: poll h(t) tagged words (tid 64..255; own quarter bypassed)
//   c. barrier A; h-dot + merge x-partials + single shfl reduce + bias ->
//      gl write; x(t+2) -> LDS xbf; barrier B
//   d. phase3 (tid<64): gates, c, h, publish-first (atomic exchange), LDS
//      own-quarter bypass, nontemporal out store.
// Weights: W_hh AND W_ih as bf16 pairs in 64 packed u32/thread (~105 VGPR,
// fits 128 cap at 16 waves/CU). f32 h/x/accum. Exchange protocol byte-
// identical to verified R2/R10 (tagged 8B words, 2-parity back-pressure).

#define TT 2048
#define BB 64
#define HH 256
#define GG 1024  // 4H

// ws layout
#define EXCH_OFF 0  // 64 x 2 x 256 x 8B = 256 KiB

__device__ __forceinline__ float sigm(float x) { return 1.0f / (1.0f + __expf(-x)); }
__device__ __forceinline__ float tanh_(float x) {
  float e = __expf(2.0f * x);
  return 1.0f - 2.0f / (e + 1.0f);
}

// pack two f32 into one u32 of bf16s (round-to-nearest-even; weights finite)
__device__ __forceinline__ unsigned int pkbf(float a, float b) {
  unsigned int ua = __float_as_uint(a), ub = __float_as_uint(b);
  ua = (ua + 0x7FFFu + ((ua >> 16) & 1u)) >> 16;
  ub = (ub + 0x7FFFu + ((ub >> 16) & 1u)) >> 16;
  return ua | (ub << 16);
}

// ---------------- fused recurrence ----------------
__global__ __launch_bounds__(1024, 1) void lstm_rec(
    const float* __restrict__ xin,  // [T,B,256]
    const float* __restrict__ h0, const float* __restrict__ c0,
    const float* __restrict__ Wih,  // [1024,256]
    const float* __restrict__ Whh,  // [1024,256]
    const float* __restrict__ bih, const float* __restrict__ bhh,
    float* __restrict__ out,        // f32: [T,B,256] ++ hT ++ cT
    unsigned long long* exch,       // [64][2][256] tagged f32
    int t0, int t1)
{
  const int tid = threadIdx.x;
  const int wblk = blockIdx.x;
  // XCD-swizzle: a batch's 4 wgs share blockIdx%8 (perf heuristic only).
  const int r = wblk & 7, q = (wblk >> 3) & 3, s5 = wblk >> 5;
  const int b = 8 * s5 + r;  // batch 0..63

  const int rg = tid >> 4;  // row group 0..63 (rows 4rg..4rg+3 of this wg)
  const int kc = tid & 15;  // K-chunk 0..15 (float4 indices kc+16j)
  const int g = rg >> 4;    // gate 0..3
  const int grow0 = 256 * g + 64 * q + 4 * (rg & 15);  // first of 4 rows/cols

  // 4x16 weight blocks, bf16-packed: whh/wih[8r + 2j + c2].
  unsigned int whh[32], wih[32];
  {
#pragma unroll
    for (int rr = 0; rr < 4; ++rr) {
      const float4* hp = (const float4*)(Whh + (size_t)(grow0 + rr) * HH);
      const float4* ip = (const float4*)(Wih + (size_t)(grow0 + rr) * HH);
#pragma unroll
      for (int j = 0; j < 4; ++j) {
        float4 wh = hp[kc + 16 * j];
        float4 wi = ip[kc + 16 * j];
        whh[8 * rr + 2 * j + 0] = pkbf(wh.x, wh.y);
        whh[8 * rr + 2 * j + 1] = pkbf(wh.z, wh.w);
        wih[8 * rr + 2 * j + 0] = pkbf(wi.x, wi.y);
        wih[8 * rr + 2 * j + 1] = pkbf(wi.z, wi.w);
      }
    }
  }

  // bias for this thread's 4 rows (only the kc==0 lane uses it)
  const bool xgl = (kc == 0);
  float4 bias4 = make_float4(0.f, 0.f, 0.f, 0.f);
  if (xgl) {
    float4 bi = *(const float4*)(bih + grow0);
    float4 bh = *(const float4*)(bhh + grow0);
    bias4 = make_float4(bi.x + bh.x, bi.y + bh.y, bi.z + bh.z, bi.w + bh.w);
  }

  float cst = 0.f;
  if (tid < 64) cst = c0[b * HH + 64 * q + tid];

  __shared__ __align__(16) float hbf[256];
  __shared__ __align__(16) float gl[256];
  __shared__ __align__(16) float xbf[2][256];  // x rows, parity double-buffer

  unsigned long long* exb = exch + b * 512;  // 2 parity slots x 256
  const int sidx = (tid + 64 * q) & 255;     // own quarter mapped to [64,256)

  // ---- prologue: x(t0) and x(t0+1) into LDS; xdot(t0) partials into regs ----
  if (tid < 64) {
    *(float4*)&xbf[t0 & 1][4 * tid] =
        *(const float4*)(xin + ((size_t)t0 * BB + b) * HH + 4 * tid);
    if (t0 + 1 < t1)
      *(float4*)&xbf[(t0 + 1) & 1][4 * tid] =
          *(const float4*)(xin + ((size_t)(t0 + 1) * BB + b) * HH + 4 * tid);
  }
  __syncthreads();

  float xc0 = 0.f, xc1 = 0.f, xc2 = 0.f, xc3 = 0.f;  // xdot partials for t
  {
    const float4* xq = (const float4*)&xbf[t0 & 1][0];
#pragma unroll
    for (int j = 0; j < 4; ++j) {
      float4 x4 = xq[kc + 16 * j];
#pragma unroll
      for (int rr = 0; rr < 4; ++rr) {
        const unsigned int wa = wih[8 * rr + 2 * j + 0];
        const unsigned int wb_ = wih[8 * rr + 2 * j + 1];
        const float w0 = __uint_as_float(wa << 16);
        const float w1 = __uint_as_float(wa & 0xFFFF0000u);
        const float w2 = __uint_as_float(wb_ << 16);
        const float w3 = __uint_as_float(wb_ & 0xFFFF0000u);
        float acc = (rr == 0) ? xc0 : (rr == 1) ? xc1 : (rr == 2) ? xc2 : xc3;
        acc = fmaf(w0, x4.x, acc);
        acc = fmaf(w1, x4.y, acc);
        acc = fmaf(w2, x4.z, acc);
        acc = fmaf(w3, x4.w, acc);
        if (rr == 0) xc0 = acc; else if (rr == 1) xc1 = acc;
        else if (rr == 2) xc2 = acc; else xc3 = acc;
      }
    }
  }

  for (int t = t0; t < t1; ++t) {
    // ---- step a: xdot(t+1) partials (RT shadow) + issue x(t+2) load ----
    float4 xpre = make_float4(0.f, 0.f, 0.f, 0.f);
    if (tid < 64 && t + 2 < t1)
      xpre = *(const float4*)(xin + ((size_t)(t + 2) * BB + b) * HH + 4 * tid);

    float xn0 = 0.f, xn1 = 0.f, xn2 = 0.f, xn3 = 0.f;
    if (t + 1 < t1) {
      const float4* xq = (const float4*)&xbf[(t + 1) & 1][0];
#pragma unroll
      for (int j = 0; j < 4; ++j) {
        float4 x4 = xq[kc + 16 * j];
#pragma unroll
        for (int rr = 0; rr < 4; ++rr) {
          const unsigned int wa = wih[8 * rr + 2 * j + 0];
          const unsigned int wb_ = wih[8 * rr + 2 * j + 1];
          const float w0 = __uint_as_float(wa << 16);
          const float w1 = __uint_as_float(wa & 0xFFFF0000u);
          const float w2 = __uint_as_float(wb_ << 16);
          const float w3 = __uint_as_float(wb_ & 0xFFFF0000u);
          float acc = (rr == 0) ? xn0 : (rr == 1) ? xn1 : (rr == 2) ? xn2 : xn3;
          acc = fmaf(w0, x4.x, acc);
          acc = fmaf(w1, x4.y, acc);
          acc = fmaf(w2, x4.z, acc);
          acc = fmaf(w3, x4.w, acc);
          if (rr == 0) xn0 = acc; else if (rr == 1) xn1 = acc;
          else if (rr == 2) xn2 = acc; else xn3 = acc;
        }
      }
    }

    // ---- phase 1: h(t) -> LDS (poll; own quarter bypassed in steady state) ----
    if (t == 0) {
      if (tid < 256) hbf[sidx] = h0[b * HH + sidx];
    } else if (t == t0 || (tid >= 64 && tid < 256)) {
      if (tid < 256) {
        unsigned long long* slot = exb + ((t & 1) << 8) + sidx;
        unsigned long long wd;
        do {
          wd = __hip_atomic_load(slot, __ATOMIC_RELAXED, __HIP_MEMORY_SCOPE_AGENT);
        } while ((unsigned int)(wd >> 32) != (unsigned int)t);
        union { unsigned int i; float f; } cv;
        cv.i = (unsigned int)wd;
        hbf[sidx] = cv.f;
      }
    }
    __syncthreads();  // barrier A: hbf complete

    // ---- step c: h-dot + merge x partials, single reduce, gl write ----
    float ac0 = xc0, ac1 = xc1, ac2 = xc2, ac3 = xc3;
    {
      const float4* hq = (const float4*)hbf;
#pragma unroll
      for (int j = 0; j < 4; ++j) {
        float4 h4 = hq[kc + 16 * j];  // 2-way alias + 4-lane bcast: free
#pragma unroll
        for (int rr = 0; rr < 4; ++rr) {
          const unsigned int wa = whh[8 * rr + 2 * j + 0];
          const unsigned int wb_ = whh[8 * rr + 2 * j + 1];
          const float w0 = __uint_as_float(wa << 16);
          const float w1 = __uint_as_float(wa & 0xFFFF0000u);
          const float w2 = __uint_as_float(wb_ << 16);
          const float w3 = __uint_as_float(wb_ & 0xFFFF0000u);
          float acc = (rr == 0) ? ac0 : (rr == 1) ? ac1 : (rr == 2) ? ac2 : ac3;
          acc = fmaf(w0, h4.x, acc);
          acc = fmaf(w1, h4.y, acc);
          acc = fmaf(w2, h4.z, acc);
          acc = fmaf(w3, h4.w, acc);
          if (rr == 0) ac0 = acc; else if (rr == 1) ac1 = acc;
          else if (rr == 2) ac2 = acc; else ac3 = acc;
        }
      }
    }
#pragma unroll
    for (int m = 1; m < 16; m <<= 1) {
      ac0 += __shfl_xor(ac0, m);
      ac1 += __shfl_xor(ac1, m);
      ac2 += __shfl_xor(ac2, m);
      ac3 += __shfl_xor(ac3, m);
    }
    if (xgl) {
      float4 o = make_float4(ac0 + bias4.x, ac1 + bias4.y,
                             ac2 + bias4.z, ac3 + bias4.w);
      *(float4*)(&gl[4 * rg]) = o;
    }
    // x(t+2) -> LDS (consumed at iter t+1 step a, after barrier B)
    if (tid < 64 && t + 2 < t1) *(float4*)&xbf[t & 1][4 * tid] = xpre;
    xc0 = xn0; xc1 = xn1; xc2 = xn2; xc3 = xn3;
    __syncthreads();  // barrier B: gl complete

    // ---- phase 3: elementwise + publish (threads 0..63 = wave 0) ----
    if (tid < 64) {
      const float gi = gl[tid];
      const float gf = gl[64 + tid];
      const float gg = gl[128 + tid];
      const float go = gl[192 + tid];
      const float ig = sigm(gi), fg = sigm(gf), gc = tanh_(gg), og = sigm(go);
      cst = fg * cst + ig * gc;
      const float hv = og * tanh_(cst);
      const int jj = 64 * q + tid;
      union { float f; unsigned int i; } hu;
      hu.f = hv;
      // publish FIRST via atomic exchange (direct to coherence point).
      __hip_atomic_exchange(exb + (((t + 1) & 1) << 8) + jj,
                            (((unsigned long long)(unsigned int)(t + 1)) << 32) | hu.i,
                            __ATOMIC_RELAXED, __HIP_MEMORY_SCOPE_AGENT);
      // own-quarter bypass for t+1 (race-free with the 2 barriers).
      hbf[jj] = hv;
      __builtin_nontemporal_store(hv, &out[(size_t)t * (BB * HH) + (size_t)b * HH + jj]);
      if (t == TT - 1) {
        const size_t base = (size_t)TT * (BB * HH);
        out[base + (size_t)b * HH + jj] = hv;             // h_T
        out[base + BB * HH + (size_t)b * HH + jj] = cst;  // c_T
      }
    }
    // hbf/gl/xbf rewrites are fenced by the next iteration's barriers.
  }
}

extern "C" void kernel_launch(void* const* d_in, const int* in_sizes, int n_in,
                              void* d_out, int out_size, void* d_ws, size_t ws_size,
                              hipStream_t stream) {
  const float* xin = (const float*)d_in[0];
  const float* h0 = (const float*)d_in[1];
  const float* c0 = (const float*)d_in[2];
  const float* Wih = (const float*)d_in[3];
  const float* Whh = (const float*)d_in[4];
  const float* bih = (const float*)d_in[5];
  const float* bhh = (const float*)d_in[6];
  float* out = (float*)d_out;

  char* ws = (char*)d_ws;
  unsigned long long* exch = (unsigned long long*)(ws + EXCH_OFF);

  hipMemsetAsync(ws + EXCH_OFF, 0, 0x40000, stream);  // clear exchange tags
  hipLaunchKernelGGL(lstm_rec, dim3(256), dim3(1024), 0, stream,
                     xin, h0, c0, Wih, Whh, bih, bhh, out, exch, 0, TT);
}